// Round 10
// baseline (155.158 us; speedup 1.0000x reference)
//
#include <hip/hip_runtime.h>
#include <math.h>

#define ALPHA 0.2f
#define LOG2E 1.44269504089f

typedef __attribute__((ext_vector_type(8))) short bf16x8;
typedef __attribute__((ext_vector_type(4))) float f32x4;

__device__ __forceinline__ float elu1(float x)  { return x > 0.f ? x : (__expf(x) - 1.f); }

// round-to-nearest-even f32 -> bf16 (finite values only)
__device__ __forceinline__ unsigned short f2bf(float x) {
    unsigned u = __float_as_uint(x);
    return (unsigned short)((u + 0x7fffu + ((u >> 16) & 1u)) >> 16);
}
__device__ __forceinline__ unsigned pkbf16(float a, float b) {
    return (unsigned)f2bf(a) | ((unsigned)f2bf(b) << 16);
}
__device__ __forceinline__ float bfs(unsigned short v) { return __uint_as_float((unsigned)v << 16); }
// round-half-up pack (a->lo, b->hi) via single v_perm on bias-added bits
__device__ __forceinline__ unsigned pkbf_rhu(float a, float b) {
    unsigned ua = __float_as_uint(a) + 0x8000u;
    unsigned ub = __float_as_uint(b) + 0x8000u;
    return __builtin_amdgcn_perm(ub, ua, 0x07060302u);
}

// ---------------------------------------------------------------------------
// Prep (single launch): W [z][K][128] f32 -> WT [z][128][K] bf16, LDS 64x64
// tile transpose. z<8: Wh (K=256); z==8: Wo (K=1024). grid (16, 2, 9).
// ---------------------------------------------------------------------------
__global__ __launch_bounds__(256) void cvt_w_all(
    const float* __restrict__ Wh, const float* __restrict__ Wo,
    unsigned short* __restrict__ WhT, unsigned short* __restrict__ WoT)
{
    const int z = blockIdx.z;
    const int K = (z < 8) ? 256 : 1024;
    if (blockIdx.x * 64 >= K) return;
    const float* in = (z < 8) ? (Wh + (size_t)z * K * 128) : Wo;
    unsigned short* out = (z < 8) ? (WhT + (size_t)z * 128 * K) : WoT;

    __shared__ float T[64][65];
    const int tid = threadIdx.x;
    const int k0 = blockIdx.x * 64, n0 = blockIdx.y * 64;

    const int kr = tid >> 4, nc = (tid & 15) * 4;
#pragma unroll
    for (int s = 0; s < 4; ++s) {
        float4 v = *(const float4*)(in + (size_t)(k0 + kr + s * 16) * 128 + n0 + nc);
        T[kr + s * 16][nc]     = v.x;
        T[kr + s * 16][nc + 1] = v.y;
        T[kr + s * 16][nc + 2] = v.z;
        T[kr + s * 16][nc + 3] = v.w;
    }
    __syncthreads();
    const int nr0 = tid >> 3, kc = (tid & 7) * 8;
#pragma unroll
    for (int s = 0; s < 2; ++s) {
        int nr = nr0 + s * 32;
        unsigned pk[4];
#pragma unroll
        for (int q = 0; q < 4; ++q)
            pk[q] = pkbf16(T[kc + 2 * q][nr], T[kc + 2 * q + 1][nr]);
        *(uint4*)(out + (size_t)(n0 + nr) * K + k0 + kc) = make_uint4(pk[0], pk[1], pk[2], pk[3]);
    }
}

// ---------------------------------------------------------------------------
// LDS-staged bf16 MFMA GEMM with transposed C store.
// AF32=1: A is f32 (x input), converted to bf16 during LDS staging
//         (requires THREADS == 4*BM).
// C^T staged via LDS aliased over As/Bs -> coalesced uint4 stores.
// DOF=1 (BN==128): fused f1/f2 head dot-products from resident C^T tile.
// ---------------------------------------------------------------------------
template <int BM, int BN, int WM, int WN, int DOF, int AF32, int THREADS>
__global__ __launch_bounds__(THREADS) void gemm_t(
    const void* __restrict__ Avp, const unsigned short* __restrict__ Bt,
    unsigned short* __restrict__ Ct, int K,
    const float* __restrict__ aV, float* __restrict__ f1g, float* __restrict__ f2g)
{
    const int RM = WM / 16, RN = WN / 16;
    const int NCA = BM * 8 / THREADS, NCB = BN * 8 / THREADS;
    constexpr int SAB_A = (BM + BN) * 72;                 // As+Bs (shorts)
    constexpr int SAB_B = BN * (BM + 8) + THREADS * 4;    // Cs + redf (shorts)
    constexpr int SAB_SH = SAB_A > SAB_B ? SAB_A : SAB_B;
    __shared__ __align__(16) unsigned short SAB[SAB_SH];
    unsigned short (*As)[72] = (unsigned short(*)[72])SAB;
    unsigned short (*Bs)[72] = (unsigned short(*)[72])(SAB + BM * 72);
    unsigned short (*Cs)[BM + 8] = (unsigned short(*)[BM + 8])SAB;   // alias
    float* redf = (float*)(SAB + BN * (BM + 8));                     // after Cs

    const int tid = threadIdx.x;
    const int w = tid >> 6, lane = tid & 63;
    const int n16 = lane & 15, quad = lane >> 4;
    const int WX = BM / WM;
    const int wm = (w % WX) * WM, wn = (w / WX) * WN;
    const int m0 = blockIdx.x * BM, n0 = blockIdx.y * BN;

    const float* Af = (const float*)Avp;
    const unsigned short* Ab = (const unsigned short*)Avp;
    const int ar = tid >> 2, akc = (tid & 3) * 16;

    f32x4 acc[RM][RN];
#pragma unroll
    for (int mm = 0; mm < RM; ++mm)
#pragma unroll
        for (int nn = 0; nn < RN; ++nn) acc[mm][nn] = (f32x4){0.f, 0.f, 0.f, 0.f};

    uint4 ra[NCA ? NCA : 1], rb[NCB];
    float4 raf[4];
    if (AF32) {
#pragma unroll
        for (int j = 0; j < 4; ++j)
            raf[j] = *(const float4*)(Af + (size_t)(m0 + ar) * K + akc + 4 * j);
    } else {
#pragma unroll
        for (int i = 0; i < NCA; ++i) {
            int c = tid * NCA + i, r = c >> 3, cc = (c & 7) * 8;
            ra[i] = *(const uint4*)(Ab + (size_t)(m0 + r) * K + cc);
        }
    }
#pragma unroll
    for (int i = 0; i < NCB; ++i) {
        int c = tid * NCB + i, r = c >> 3, cc = (c & 7) * 8;
        rb[i] = *(const uint4*)(Bt + (size_t)(n0 + r) * K + cc);
    }

    const int nk = K >> 6;
    for (int kt = 0; kt < nk; ++kt) {
        __syncthreads();
        if (AF32) {
            uint4 lo = make_uint4(pkbf16(raf[0].x, raf[0].y), pkbf16(raf[0].z, raf[0].w),
                                  pkbf16(raf[1].x, raf[1].y), pkbf16(raf[1].z, raf[1].w));
            uint4 hi = make_uint4(pkbf16(raf[2].x, raf[2].y), pkbf16(raf[2].z, raf[2].w),
                                  pkbf16(raf[3].x, raf[3].y), pkbf16(raf[3].z, raf[3].w));
            *(uint4*)&As[ar][akc]     = lo;
            *(uint4*)&As[ar][akc + 8] = hi;
        } else {
#pragma unroll
            for (int i = 0; i < NCA; ++i) {
                int c = tid * NCA + i, r = c >> 3, cc = (c & 7) * 8;
                *(uint4*)&As[r][cc] = ra[i];
            }
        }
#pragma unroll
        for (int i = 0; i < NCB; ++i) {
            int c = tid * NCB + i, r = c >> 3, cc = (c & 7) * 8;
            *(uint4*)&Bs[r][cc] = rb[i];
        }
        __syncthreads();
        if (kt + 1 < nk) {
            int k0 = (kt + 1) * 64;
            if (AF32) {
#pragma unroll
                for (int j = 0; j < 4; ++j)
                    raf[j] = *(const float4*)(Af + (size_t)(m0 + ar) * K + k0 + akc + 4 * j);
            } else {
#pragma unroll
                for (int i = 0; i < NCA; ++i) {
                    int c = tid * NCA + i, r = c >> 3, cc = (c & 7) * 8;
                    ra[i] = *(const uint4*)(Ab + (size_t)(m0 + r) * K + k0 + cc);
                }
            }
#pragma unroll
            for (int i = 0; i < NCB; ++i) {
                int c = tid * NCB + i, r = c >> 3, cc = (c & 7) * 8;
                rb[i] = *(const uint4*)(Bt + (size_t)(n0 + r) * K + k0 + cc);
            }
        }
#pragma unroll
        for (int ks = 0; ks < 2; ++ks) {
            bf16x8 am[RM], bn[RN];
#pragma unroll
            for (int mm = 0; mm < RM; ++mm)
                am[mm] = *(const bf16x8*)&As[wm + mm * 16 + n16][ks * 32 + quad * 8];
#pragma unroll
            for (int nn = 0; nn < RN; ++nn)
                bn[nn] = *(const bf16x8*)&Bs[wn + nn * 16 + n16][ks * 32 + quad * 8];
#pragma unroll
            for (int mm = 0; mm < RM; ++mm)
#pragma unroll
                for (int nn = 0; nn < RN; ++nn)
                    acc[mm][nn] = __builtin_amdgcn_mfma_f32_16x16x32_bf16(
                        am[mm], bn[nn], acc[mm][nn], 0, 0, 0);
        }
    }

    __syncthreads();   // all LDS frag reads done before Cs aliases As/Bs

    // --- epilogue: acc -> LDS bf16 tile (C^T layout: Cs[n][m]) ---
#pragma unroll
    for (int nn = 0; nn < RN; ++nn) {
        int n = wn + nn * 16 + n16;
#pragma unroll
        for (int mm = 0; mm < RM; ++mm) {
            int m = wm + mm * 16 + quad * 4;
            f32x4 a = acc[mm][nn];
            ushort4 o = make_ushort4(f2bf(a[0]), f2bf(a[1]), f2bf(a[2]), f2bf(a[3]));
            *(ushort4*)&Cs[n][m] = o;
        }
    }
    __syncthreads();

    // --- coalesced store: row n = BM shorts contiguous, uint4 chunks ---
    const int CHUNKS = BM * 2 / 16;
    const int RPP = THREADS / CHUNKS;
    const int row = tid / CHUNKS, ch = tid % CHUNKS;
#pragma unroll
    for (int s = 0; s < BN / RPP; ++s) {
        int n = row + s * RPP;
        *(uint4*)(Ct + (size_t)(n0 + n) * 8192 + m0 + ch * 8) =
            *(const uint4*)&Cs[n][ch * 8];
    }

    // --- fused f1/f2 (one head resident: BN==128) ---
    if (DOF) {
        const int G = THREADS / BM;      // thread groups over f
        const int FP = 128 / G;          // f's per group
        const int mloc = tid % BM, fq = tid / BM;
        const float* az = aV + blockIdx.y * 256;
        float s1 = 0.f, s2 = 0.f;
#pragma unroll 8
        for (int k = 0; k < FP; ++k) {
            int f = fq * FP + k;
            float h = bfs(Cs[f][mloc]);
            s1 += h * az[f];
            s2 += h * az[128 + f];
        }
        *(float2*)&redf[(fq * BM + mloc) * 2] = make_float2(s1, s2);
        __syncthreads();
        if (tid < BM) {
            float a1 = 0.f, a2 = 0.f;
#pragma unroll
            for (int g = 0; g < G; ++g) {
                a1 += redf[(g * BM + tid) * 2];
                a2 += redf[(g * BM + tid) * 2 + 1];
            }
            f1g[(size_t)blockIdx.y * 8192 + m0 + tid] = a1;
            f2g[(size_t)blockIdx.y * 8192 + m0 + tid] = a2;
        }
    }
}

// ---------------------------------------------------------------------------
// MFMA attention (layer 1) — Ai-cancelled exp-free inner loop, dbuf JT=128.
// q_ij = max(u_j, r_i*v_j); Ai factor cancels vs ones-MFMA lsum.
// NI=4, NT=4, FS=2 (f-split): per-wave i-parallelism in registers + f-halved
// B-fragment reads -> per-CU LDS kk-traffic 96->64 b128 at same outputs.
// dbuf JT=128 pipeline retained (R6-proven); 8 waves (2/SIMD) retained.
// grid (8=hy, 2=ibx, 16=bz*2+fz), 256 blocks (1/CU). LDS ~43 KB.
// ---------------------------------------------------------------------------
template <int NI, int NT, int THREADS, int FS>
__global__ __launch_bounds__(THREADS) void attn4(
    const unsigned short* __restrict__ hT, const float* __restrict__ f1g,
    const float* __restrict__ f2g, unsigned short* __restrict__ outb)
{
    const int N = 1024, JT = 128, JP = JT + 8;
    const int KKN = JT / 32;                 // kk slices per tile
    const int NW = THREADS / 64;             // waves per block
    const int ITILE = 16 * NI * NW;          // i-rows per block
    const int SJW = JT / 8;                  // threads per staged row
    const int SR = THREADS / SJW;            // rows per stage chunk
    const int NTS = NT * 16 / SR;            // stage chunks per thread
    const int EPT = 1024 / THREADS;          // ul/vl elems per thread
    __shared__ __align__(16) unsigned short hls[2][NT * 16][JP];
    __shared__ float ul[1024], vl[1024];
    __shared__ float wred[NW];

    const int tid = threadIdx.x;
    const int w = tid >> 6, lane = tid & 63;
    const int n16 = lane & 15, quad = lane >> 4;
    const int hy = blockIdx.x;
    const int ibx = blockIdx.y;
    const int bz = (FS == 2) ? (blockIdx.z >> 1) : blockIdx.z;
    const int fz = (FS == 2) ? (blockIdx.z & 1) : 0;
    const int hb = hy * 8 + bz;
    const int iw0 = ibx * ITILE + w * (16 * NI);

    // raw f2L -> ul (temp) + per-wave max
    if (EPT == 4) {
        const int j4 = tid * 4;
        float4 fv = *(const float4*)(f2g + (size_t)hb * N + j4);
        fv.x *= LOG2E; fv.y *= LOG2E; fv.z *= LOG2E; fv.w *= LOG2E;
        *(float4*)&ul[j4] = fv;
        float m4 = fmaxf(fmaxf(fv.x, fv.y), fmaxf(fv.z, fv.w));
#pragma unroll
        for (int off = 32; off; off >>= 1) m4 = fmaxf(m4, __shfl_xor(m4, off));
        if (lane == 0) wred[w] = m4;
    } else {
        const int j2 = tid * 2;
        float2 fv = *(const float2*)(f2g + (size_t)hb * N + j2);
        fv.x *= LOG2E; fv.y *= LOG2E;
        *(float2*)&ul[j2] = fv;
        float m4 = fmaxf(fv.x, fv.y);
#pragma unroll
        for (int off = 32; off; off >>= 1) m4 = fmaxf(m4, __shfl_xor(m4, off));
        if (lane == 0) wred[w] = m4;
    }

    float f1L[NI];
#pragma unroll
    for (int ii = 0; ii < NI; ++ii)
        f1L[ii] = f1g[(size_t)hb * N + iw0 + ii * 16 + n16] * LOG2E;

    const unsigned short* gsrc = hT + (size_t)(hy * 128 + fz * (NT * 16)) * 8192 + bz * 1024;
    const int sf = tid / SJW, sj = (tid % SJW) * 8;

    bf16x8 stg[NTS];
#pragma unroll
    for (int s = 0; s < NTS; ++s)
        stg[s] = *(const bf16x8*)(gsrc + (size_t)(sf + SR * s) * 8192 + sj);

    __syncthreads();   // ul(raw)/wred visible
    float f2mL = wred[0];
#pragma unroll
    for (int k = 1; k < NW; ++k) f2mL = fmaxf(f2mL, wred[k]);

    // rewrite own slots: u = exp2(raw - f2mL), v = exp2(a*(raw - f2mL))
    if (EPT == 4) {
        const int j4 = tid * 4;
        float4 raw = *(const float4*)&ul[j4];
        float4 uu, vv;
        float d0 = raw.x - f2mL, d1 = raw.y - f2mL, d2 = raw.z - f2mL, d3 = raw.w - f2mL;
        uu.x = __builtin_amdgcn_exp2f(d0); vv.x = __builtin_amdgcn_exp2f(ALPHA * d0);
        uu.y = __builtin_amdgcn_exp2f(d1); vv.y = __builtin_amdgcn_exp2f(ALPHA * d1);
        uu.z = __builtin_amdgcn_exp2f(d2); vv.z = __builtin_amdgcn_exp2f(ALPHA * d2);
        uu.w = __builtin_amdgcn_exp2f(d3); vv.w = __builtin_amdgcn_exp2f(ALPHA * d3);
        *(float4*)&ul[j4] = uu;
        *(float4*)&vl[j4] = vv;
    } else {
        const int j2 = tid * 2;
        float2 raw = *(const float2*)&ul[j2];
        float d0 = raw.x - f2mL, d1 = raw.y - f2mL;
        float2 uu, vv;
        uu.x = __builtin_amdgcn_exp2f(d0); vv.x = __builtin_amdgcn_exp2f(ALPHA * d0);
        uu.y = __builtin_amdgcn_exp2f(d1); vv.y = __builtin_amdgcn_exp2f(ALPHA * d1);
        *(float2*)&ul[j2] = uu;
        *(float2*)&vl[j2] = vv;
    }

    float ri[NI];
#pragma unroll
    for (int ii = 0; ii < NI; ++ii)
        ri[ii] = __builtin_amdgcn_exp2f((ALPHA - 1.f) * (f1L[ii] + f2mL));

    f32x4 acc[NI][NT], accl[NI];
#pragma unroll
    for (int ii = 0; ii < NI; ++ii) {
        accl[ii] = (f32x4){0.f, 0.f, 0.f, 0.f};
#pragma unroll
        for (int t = 0; t < NT; ++t) acc[ii][t] = (f32x4){0.f, 0.f, 0.f, 0.f};
    }
    bf16x8 ones;
    { union { bf16x8 v; unsigned u[4]; } o;
      o.u[0] = o.u[1] = o.u[2] = o.u[3] = 0x3F803F80u; ones = o.v; }

    // stage tile 0 into buf 0
#pragma unroll
    for (int s = 0; s < NTS; ++s)
        *(bf16x8*)&hls[0][sf + SR * s][sj] = stg[s];
    __syncthreads();   // tile 0 + rewritten ul/vl visible

    for (int jt = 0; jt < N / JT; ++jt) {
        const int cur = jt & 1;
        if (jt + 1 < N / JT) {
            int j0n = (jt + 1) * JT;
#pragma unroll
            for (int s = 0; s < NTS; ++s)
                stg[s] = *(const bf16x8*)(gsrc + (size_t)(sf + SR * s) * 8192 + j0n + sj);
        }
        const int j0 = jt * JT;
#pragma unroll
        for (int kk = 0; kk < KKN; ++kk) {
            const int jb = j0 + kk * 32 + quad * 8;
            float4 u0 = *(const float4*)&ul[jb], u1 = *(const float4*)&ul[jb + 4];
            float4 v0 = *(const float4*)&vl[jb], v1 = *(const float4*)&vl[jb + 4];
            float uj[8] = {u0.x, u0.y, u0.z, u0.w, u1.x, u1.y, u1.z, u1.w};
            float vj[8] = {v0.x, v0.y, v0.z, v0.w, v1.x, v1.y, v1.z, v1.w};

            bf16x8 afr[NI];
#pragma unroll
            for (int ii = 0; ii < NI; ++ii) {
                union { bf16x8 v; unsigned u[4]; } cvt;
#pragma unroll
                for (int q = 0; q < 4; ++q) {
                    float p0 = fmaxf(uj[2 * q],     ri[ii] * vj[2 * q]);
                    float p1 = fmaxf(uj[2 * q + 1], ri[ii] * vj[2 * q + 1]);
                    cvt.u[q] = pkbf_rhu(p0, p1);
                }
                afr[ii] = cvt.v;
            }
            __builtin_amdgcn_s_setprio(1);
#pragma unroll
            for (int t = 0; t < NT; ++t) {
                bf16x8 bfr = *(const bf16x8*)&hls[cur][t * 16 + n16][kk * 32 + quad * 8];
#pragma unroll
                for (int ii = 0; ii < NI; ++ii)
                    acc[ii][t] = __builtin_amdgcn_mfma_f32_16x16x32_bf16(
                        afr[ii], bfr, acc[ii][t], 0, 0, 0);
            }
#pragma unroll
            for (int ii = 0; ii < NI; ++ii)
                accl[ii] = __builtin_amdgcn_mfma_f32_16x16x32_bf16(
                    afr[ii], ones, accl[ii], 0, 0, 0);
            __builtin_amdgcn_s_setprio(0);
        }
        if (jt + 1 < N / JT) {
#pragma unroll
            for (int s = 0; s < NTS; ++s)
                *(bf16x8*)&hls[1 - cur][sf + SR * s][sj] = stg[s];
        }
        __syncthreads();
    }

    // epilogue: C/D layout col=lane&15 (f), row=quad*4+reg (i); lsum in accl
#pragma unroll
    for (int ii = 0; ii < NI; ++ii) {
#pragma unroll
        for (int r = 0; r < 4; ++r) {
            float inv = 1.f / accl[ii][r];
            int i = iw0 + ii * 16 + quad * 4 + r;
#pragma unroll
            for (int t = 0; t < NT; ++t) {
                float tv = acc[ii][t][r] * inv;
                tv = elu1(tv);
                outb[(size_t)(bz * 1024 + i) * 1024 + hy * 128 + fz * (NT * 16) + t * 16 + n16]
                    = f2bf(tv);
            }
        }
    }
}

// ---------------------------------------------------------------------------
// MFMA attention (layer 2) — stage-once barrier-free variant (R4-proven).
// Per block: full 64f x 1024j slice resident in LDS (129 KB, pad 1032 rows
// -> ~2-way bank aliasing = free), 2 barriers total, then 16 jt iterations
// of pure p-build+MFMA with no syncs. f-split via blockIdx.z.
// grid (8=bz, 16=ibx, 2=fz), 256 threads. Output f32 with double elu.
// ---------------------------------------------------------------------------
__global__ __launch_bounds__(256) void attn5(
    const unsigned short* __restrict__ hT, const float* __restrict__ f1g,
    const float* __restrict__ f2g, float* __restrict__ outf)
{
    const int N = 1024;
    __shared__ __align__(16) unsigned short hfull[64][1032];
    __shared__ float ul[1024], vl[1024];
    __shared__ float wred[4];

    const int tid = threadIdx.x;
    const int w = tid >> 6, lane = tid & 63;
    const int n16 = lane & 15, quad = lane >> 4;
    const int bz = blockIdx.x;
    const int ibx = blockIdx.y;
    const int fz = blockIdx.z;
    const int iw0 = ibx * 64 + w * 16;

    // raw f2L -> ul (temp) + per-wave max
    const int j4 = tid * 4;
    {
        float4 fv = *(const float4*)(f2g + (size_t)bz * N + j4);
        fv.x *= LOG2E; fv.y *= LOG2E; fv.z *= LOG2E; fv.w *= LOG2E;
        *(float4*)&ul[j4] = fv;
        float m4 = fmaxf(fmaxf(fv.x, fv.y), fmaxf(fv.z, fv.w));
#pragma unroll
        for (int off = 32; off; off >>= 1) m4 = fmaxf(m4, __shfl_xor(m4, off));
        if (lane == 0) wred[w] = m4;
    }

    float f1L = f1g[(size_t)bz * N + iw0 + n16] * LOG2E;

    // stage the whole 64 x 1024 slice (once)
    const unsigned short* gsrc = hT + (size_t)(fz * 64) * 8192 + bz * 1024;
    const int sr = tid >> 3;            // 0..31
    const int sc = (tid & 7) * 8;       // 0..56
#pragma unroll
    for (int s = 0; s < 2; ++s)
#pragma unroll
        for (int c = 0; c < 16; ++c)
            *(bf16x8*)&hfull[sr + 32 * s][sc + c * 64] =
                *(const bf16x8*)(gsrc + (size_t)(sr + 32 * s) * 8192 + sc + c * 64);

    __syncthreads();   // ul(raw)/wred visible (stage writes also complete later)
    const float f2mL = fmaxf(fmaxf(wred[0], wred[1]), fmaxf(wred[2], wred[3]));

    // rewrite own slots: u = exp2(raw - f2mL), v = exp2(a*(raw - f2mL))
    {
        float4 raw = *(const float4*)&ul[j4];
        float4 uu, vv;
        float d0 = raw.x - f2mL, d1 = raw.y - f2mL, d2 = raw.z - f2mL, d3 = raw.w - f2mL;
        uu.x = __builtin_amdgcn_exp2f(d0); vv.x = __builtin_amdgcn_exp2f(ALPHA * d0);
        uu.y = __builtin_amdgcn_exp2f(d1); vv.y = __builtin_amdgcn_exp2f(ALPHA * d1);
        uu.z = __builtin_amdgcn_exp2f(d2); vv.z = __builtin_amdgcn_exp2f(ALPHA * d2);
        uu.w = __builtin_amdgcn_exp2f(d3); vv.w = __builtin_amdgcn_exp2f(ALPHA * d3);
        *(float4*)&ul[j4] = uu;
        *(float4*)&vl[j4] = vv;
    }
    const float ri = __builtin_amdgcn_exp2f((ALPHA - 1.f) * (f1L + f2mL));

    f32x4 acc[4], accl = (f32x4){0.f, 0.f, 0.f, 0.f};
#pragma unroll
    for (int t = 0; t < 4; ++t) acc[t] = (f32x4){0.f, 0.f, 0.f, 0.f};
    bf16x8 ones;
    { union { bf16x8 v; unsigned u[4]; } o;
      o.u[0] = o.u[1] = o.u[2] = o.u[3] = 0x3F803F80u; ones = o.v; }

    __syncthreads();   // rewritten ul/vl + full stage visible

    for (int jt = 0; jt < 16; ++jt) {
#pragma unroll
        for (int kk = 0; kk < 2; ++kk) {
            const int jb = jt * 64 + kk * 32 + quad * 8;
            float4 u0 = *(const float4*)&ul[jb], u1 = *(const float4*)&ul[jb + 4];
            float4 v0 = *(const float4*)&vl[jb], v1 = *(const float4*)&vl[jb + 4];
            float uj[8] = {u0.x, u0.y, u0.z, u0.w, u1.x, u1.y, u1.z, u1.w};
            float vj[8] = {v0.x, v0.y, v0.z, v0.w, v1.x, v1.y, v1.z, v1.w};

            union { bf16x8 v; unsigned u[4]; } cvt;
#pragma unroll
            for (int q = 0; q < 4; ++q) {
                float p0 = fmaxf(uj[2 * q],     ri * vj[2 * q]);
                float p1 = fmaxf(uj[2 * q + 1], ri * vj[2 * q + 1]);
                cvt.u[q] = pkbf_rhu(p0, p1);
            }
            bf16x8 afr = cvt.v;
            __builtin_amdgcn_s_setprio(1);
#pragma unroll
            for (int t = 0; t < 4; ++t) {
                bf16x8 bfr = *(const bf16x8*)&hfull[t * 16 + n16][jb];
                acc[t] = __builtin_amdgcn_mfma_f32_16x16x32_bf16(afr, bfr, acc[t], 0, 0, 0);
            }
            accl = __builtin_amdgcn_mfma_f32_16x16x32_bf16(afr, ones, accl, 0, 0, 0);
            __builtin_amdgcn_s_setprio(0);
        }
    }

    // epilogue: col=lane&15 (f), row=quad*4+reg (i); double elu; f32 out
#pragma unroll
    for (int r = 0; r < 4; ++r) {
        float inv = 1.f / accl[r];
        int i = iw0 + quad * 4 + r;
#pragma unroll
        for (int t = 0; t < 4; ++t) {
            float tv = elu1(elu1(acc[t][r] * inv));
            outf[(size_t)(bz * 1024 + i) * 128 + fz * 64 + t * 16 + n16] = tv;
        }
    }
}

// ---------------------------------------------------------------------------
// B=8, N=1024, D=256, H=8, F=128
// ---------------------------------------------------------------------------
extern "C" void kernel_launch(void* const* d_in, const int* in_sizes, int n_in,
                              void* d_out, int out_size, void* d_ws, size_t ws_size,
                              hipStream_t stream)
{
    const float* x  = (const float*)d_in[0];
    const float* Wh = (const float*)d_in[2];
    const float* ah = (const float*)d_in[3];
    const float* Wo = (const float*)d_in[4];
    const float* ao = (const float*)d_in[5];
    float* out = (float*)d_out;

    unsigned short* WhT = (unsigned short*)d_ws;       // [1024][256]
    unsigned short* WoT = WhT + 262144;                // [128][1024]
    unsigned short* h1T = WoT + 131072;                // [8][128][8192]
    unsigned short* xcb = h1T + 8388608;               // [8192][1024]
    unsigned short* h2T = xcb + 8388608;               // [128][8192]
    float* f1a  = (float*)(h2T + 1048576);             // [8][8192]
    float* f2a  = f1a + 65536;                         // [8][8192]
    float* f1b  = f2a + 65536;                         // [8192]
    float* f2b  = f1b + 8192;                          // [8192]

    // prep: both weight transposes in one launch
    cvt_w_all<<<dim3(16, 2, 9), 256, 0, stream>>>(Wh, Wo, WhT, WoT);

    // Layer 1: fused x-convert + GEMM (128x128 tile) + f1/f2 epilogue,
    // then dbuf attention: NI=4/NT=4 f-split (halved LDS kk-traffic)
    gemm_t<128, 128, 32, 64, 1, 1, 512><<<dim3(64, 8), 512, 0, stream>>>(
        x, WhT, h1T, 256, ah, f1a, f2a);
    attn4<4, 4, 512, 2><<<dim3(8, 2, 16), 512, 0, stream>>>(h1T, f1a, f2a, xcb);

    // Layer 2: GEMM with fused f1/f2 epilogue, then stage-once attention
    gemm_t<32, 128, 16, 64, 1, 0, 256><<<dim3(256, 1), 256, 0, stream>>>(
        xcb, WoT, h2T, 1024, ao, f1b, f2b);
    attn5<<<dim3(8, 16, 2), 256, 0, stream>>>(h2T, f1b, f2b, out);
}

// Round 11
// 151.259 us; speedup vs baseline: 1.0258x; 1.0258x over previous
//
#include <hip/hip_runtime.h>
#include <math.h>

#define ALPHA 0.2f
#define LOG2E 1.44269504089f

typedef __attribute__((ext_vector_type(8))) short bf16x8;
typedef __attribute__((ext_vector_type(4))) float f32x4;

__device__ __forceinline__ float elu1(float x)  { return x > 0.f ? x : (__expf(x) - 1.f); }

// round-to-nearest-even f32 -> bf16 (finite values only)
__device__ __forceinline__ unsigned short f2bf(float x) {
    unsigned u = __float_as_uint(x);
    return (unsigned short)((u + 0x7fffu + ((u >> 16) & 1u)) >> 16);
}
__device__ __forceinline__ unsigned pkbf16(float a, float b) {
    return (unsigned)f2bf(a) | ((unsigned)f2bf(b) << 16);
}
__device__ __forceinline__ float bfs(unsigned short v) { return __uint_as_float((unsigned)v << 16); }
// round-half-up pack (a->lo, b->hi) via single v_perm on bias-added bits
__device__ __forceinline__ unsigned pkbf_rhu(float a, float b) {
    unsigned ua = __float_as_uint(a) + 0x8000u;
    unsigned ub = __float_as_uint(b) + 0x8000u;
    return __builtin_amdgcn_perm(ub, ua, 0x07060302u);
}

// ---------------------------------------------------------------------------
// Prep (single launch): W [z][K][128] f32 -> WT [z][128][K] bf16, LDS 64x64
// tile transpose. z<8: Wh (K=256); z==8: Wo (K=1024). grid (16, 2, 9).
// ---------------------------------------------------------------------------
__global__ __launch_bounds__(256) void cvt_w_all(
    const float* __restrict__ Wh, const float* __restrict__ Wo,
    unsigned short* __restrict__ WhT, unsigned short* __restrict__ WoT)
{
    const int z = blockIdx.z;
    const int K = (z < 8) ? 256 : 1024;
    if (blockIdx.x * 64 >= K) return;
    const float* in = (z < 8) ? (Wh + (size_t)z * K * 128) : Wo;
    unsigned short* out = (z < 8) ? (WhT + (size_t)z * 128 * K) : WoT;

    __shared__ float T[64][65];
    const int tid = threadIdx.x;
    const int k0 = blockIdx.x * 64, n0 = blockIdx.y * 64;

    const int kr = tid >> 4, nc = (tid & 15) * 4;
#pragma unroll
    for (int s = 0; s < 4; ++s) {
        float4 v = *(const float4*)(in + (size_t)(k0 + kr + s * 16) * 128 + n0 + nc);
        T[kr + s * 16][nc]     = v.x;
        T[kr + s * 16][nc + 1] = v.y;
        T[kr + s * 16][nc + 2] = v.z;
        T[kr + s * 16][nc + 3] = v.w;
    }
    __syncthreads();
    const int nr0 = tid >> 3, kc = (tid & 7) * 8;
#pragma unroll
    for (int s = 0; s < 2; ++s) {
        int nr = nr0 + s * 32;
        unsigned pk[4];
#pragma unroll
        for (int q = 0; q < 4; ++q)
            pk[q] = pkbf16(T[kc + 2 * q][nr], T[kc + 2 * q + 1][nr]);
        *(uint4*)(out + (size_t)(n0 + nr) * K + k0 + kc) = make_uint4(pk[0], pk[1], pk[2], pk[3]);
    }
}

// ---------------------------------------------------------------------------
// LDS-staged bf16 MFMA GEMM with transposed C store.
// AF32=1: A is f32 (x input), converted to bf16 during LDS staging
//         (requires THREADS == 4*BM).
// C^T staged via LDS aliased over As/Bs -> coalesced uint4 stores.
// DOF=1 (BN==128): fused f1/f2 head dot-products from resident C^T tile.
// ---------------------------------------------------------------------------
template <int BM, int BN, int WM, int WN, int DOF, int AF32, int THREADS>
__global__ __launch_bounds__(THREADS) void gemm_t(
    const void* __restrict__ Avp, const unsigned short* __restrict__ Bt,
    unsigned short* __restrict__ Ct, int K,
    const float* __restrict__ aV, float* __restrict__ f1g, float* __restrict__ f2g)
{
    const int RM = WM / 16, RN = WN / 16;
    const int NCA = BM * 8 / THREADS, NCB = BN * 8 / THREADS;
    constexpr int SAB_A = (BM + BN) * 72;                 // As+Bs (shorts)
    constexpr int SAB_B = BN * (BM + 8) + THREADS * 4;    // Cs + redf (shorts)
    constexpr int SAB_SH = SAB_A > SAB_B ? SAB_A : SAB_B;
    __shared__ __align__(16) unsigned short SAB[SAB_SH];
    unsigned short (*As)[72] = (unsigned short(*)[72])SAB;
    unsigned short (*Bs)[72] = (unsigned short(*)[72])(SAB + BM * 72);
    unsigned short (*Cs)[BM + 8] = (unsigned short(*)[BM + 8])SAB;   // alias
    float* redf = (float*)(SAB + BN * (BM + 8));                     // after Cs

    const int tid = threadIdx.x;
    const int w = tid >> 6, lane = tid & 63;
    const int n16 = lane & 15, quad = lane >> 4;
    const int WX = BM / WM;
    const int wm = (w % WX) * WM, wn = (w / WX) * WN;
    const int m0 = blockIdx.x * BM, n0 = blockIdx.y * BN;

    const float* Af = (const float*)Avp;
    const unsigned short* Ab = (const unsigned short*)Avp;
    const int ar = tid >> 2, akc = (tid & 3) * 16;

    f32x4 acc[RM][RN];
#pragma unroll
    for (int mm = 0; mm < RM; ++mm)
#pragma unroll
        for (int nn = 0; nn < RN; ++nn) acc[mm][nn] = (f32x4){0.f, 0.f, 0.f, 0.f};

    uint4 ra[NCA ? NCA : 1], rb[NCB];
    float4 raf[4];
    if (AF32) {
#pragma unroll
        for (int j = 0; j < 4; ++j)
            raf[j] = *(const float4*)(Af + (size_t)(m0 + ar) * K + akc + 4 * j);
    } else {
#pragma unroll
        for (int i = 0; i < NCA; ++i) {
            int c = tid * NCA + i, r = c >> 3, cc = (c & 7) * 8;
            ra[i] = *(const uint4*)(Ab + (size_t)(m0 + r) * K + cc);
        }
    }
#pragma unroll
    for (int i = 0; i < NCB; ++i) {
        int c = tid * NCB + i, r = c >> 3, cc = (c & 7) * 8;
        rb[i] = *(const uint4*)(Bt + (size_t)(n0 + r) * K + cc);
    }

    const int nk = K >> 6;
    for (int kt = 0; kt < nk; ++kt) {
        __syncthreads();
        if (AF32) {
            uint4 lo = make_uint4(pkbf16(raf[0].x, raf[0].y), pkbf16(raf[0].z, raf[0].w),
                                  pkbf16(raf[1].x, raf[1].y), pkbf16(raf[1].z, raf[1].w));
            uint4 hi = make_uint4(pkbf16(raf[2].x, raf[2].y), pkbf16(raf[2].z, raf[2].w),
                                  pkbf16(raf[3].x, raf[3].y), pkbf16(raf[3].z, raf[3].w));
            *(uint4*)&As[ar][akc]     = lo;
            *(uint4*)&As[ar][akc + 8] = hi;
        } else {
#pragma unroll
            for (int i = 0; i < NCA; ++i) {
                int c = tid * NCA + i, r = c >> 3, cc = (c & 7) * 8;
                *(uint4*)&As[r][cc] = ra[i];
            }
        }
#pragma unroll
        for (int i = 0; i < NCB; ++i) {
            int c = tid * NCB + i, r = c >> 3, cc = (c & 7) * 8;
            *(uint4*)&Bs[r][cc] = rb[i];
        }
        __syncthreads();
        if (kt + 1 < nk) {
            int k0 = (kt + 1) * 64;
            if (AF32) {
#pragma unroll
                for (int j = 0; j < 4; ++j)
                    raf[j] = *(const float4*)(Af + (size_t)(m0 + ar) * K + k0 + akc + 4 * j);
            } else {
#pragma unroll
                for (int i = 0; i < NCA; ++i) {
                    int c = tid * NCA + i, r = c >> 3, cc = (c & 7) * 8;
                    ra[i] = *(const uint4*)(Ab + (size_t)(m0 + r) * K + k0 + cc);
                }
            }
#pragma unroll
            for (int i = 0; i < NCB; ++i) {
                int c = tid * NCB + i, r = c >> 3, cc = (c & 7) * 8;
                rb[i] = *(const uint4*)(Bt + (size_t)(n0 + r) * K + k0 + cc);
            }
        }
#pragma unroll
        for (int ks = 0; ks < 2; ++ks) {
            bf16x8 am[RM], bn[RN];
#pragma unroll
            for (int mm = 0; mm < RM; ++mm)
                am[mm] = *(const bf16x8*)&As[wm + mm * 16 + n16][ks * 32 + quad * 8];
#pragma unroll
            for (int nn = 0; nn < RN; ++nn)
                bn[nn] = *(const bf16x8*)&Bs[wn + nn * 16 + n16][ks * 32 + quad * 8];
#pragma unroll
            for (int mm = 0; mm < RM; ++mm)
#pragma unroll
                for (int nn = 0; nn < RN; ++nn)
                    acc[mm][nn] = __builtin_amdgcn_mfma_f32_16x16x32_bf16(
                        am[mm], bn[nn], acc[mm][nn], 0, 0, 0);
        }
    }

    __syncthreads();   // all LDS frag reads done before Cs aliases As/Bs

    // --- epilogue: acc -> LDS bf16 tile (C^T layout: Cs[n][m]) ---
#pragma unroll
    for (int nn = 0; nn < RN; ++nn) {
        int n = wn + nn * 16 + n16;
#pragma unroll
        for (int mm = 0; mm < RM; ++mm) {
            int m = wm + mm * 16 + quad * 4;
            f32x4 a = acc[mm][nn];
            ushort4 o = make_ushort4(f2bf(a[0]), f2bf(a[1]), f2bf(a[2]), f2bf(a[3]));
            *(ushort4*)&Cs[n][m] = o;
        }
    }
    __syncthreads();

    // --- coalesced store: row n = BM shorts contiguous, uint4 chunks ---
    const int CHUNKS = BM * 2 / 16;
    const int RPP = THREADS / CHUNKS;
    const int row = tid / CHUNKS, ch = tid % CHUNKS;
#pragma unroll
    for (int s = 0; s < BN / RPP; ++s) {
        int n = row + s * RPP;
        *(uint4*)(Ct + (size_t)(n0 + n) * 8192 + m0 + ch * 8) =
            *(const uint4*)&Cs[n][ch * 8];
    }

    // --- fused f1/f2 (one head resident: BN==128) ---
    if (DOF) {
        const int G = THREADS / BM;      // thread groups over f
        const int FP = 128 / G;          // f's per group
        const int mloc = tid % BM, fq = tid / BM;
        const float* az = aV + blockIdx.y * 256;
        float s1 = 0.f, s2 = 0.f;
#pragma unroll 8
        for (int k = 0; k < FP; ++k) {
            int f = fq * FP + k;
            float h = bfs(Cs[f][mloc]);
            s1 += h * az[f];
            s2 += h * az[128 + f];
        }
        *(float2*)&redf[(fq * BM + mloc) * 2] = make_float2(s1, s2);
        __syncthreads();
        if (tid < BM) {
            float a1 = 0.f, a2 = 0.f;
#pragma unroll
            for (int g = 0; g < G; ++g) {
                a1 += redf[(g * BM + tid) * 2];
                a2 += redf[(g * BM + tid) * 2 + 1];
            }
            f1g[(size_t)blockIdx.y * 8192 + m0 + tid] = a1;
            f2g[(size_t)blockIdx.y * 8192 + m0 + tid] = a2;
        }
    }
}

// ---------------------------------------------------------------------------
// MFMA attention (layer 1) — Ai-cancelled exp-free inner loop, dbuf JT=128.
// q_ij = max(u_j, r_i*v_j); Ai factor cancels vs ones-MFMA lsum.
// R9-BEST CONFIG (152.8 us): NI=2, NT=8, THREADS=512 (8 waves, 2/SIMD),
// FS=1, setprio around MFMA cluster. Probes bracketing this optimum:
// NI=4/256thr (R5, +9.5), stage-once (R7, +5.2), f-split dbuf (R10, +2.4).
// grid (8=hy, 4, 8=bz), 256 blocks (1/CU). LDS ~78 KB.
// ---------------------------------------------------------------------------
template <int NI, int NT, int THREADS, int FS>
__global__ __launch_bounds__(THREADS) void attn4(
    const unsigned short* __restrict__ hT, const float* __restrict__ f1g,
    const float* __restrict__ f2g, unsigned short* __restrict__ outb)
{
    const int N = 1024, JT = 128, JP = JT + 8;
    const int KKN = JT / 32;                 // kk slices per tile
    const int NW = THREADS / 64;             // waves per block
    const int ITILE = 16 * NI * NW;          // i-rows per block
    const int SJW = JT / 8;                  // threads per staged row
    const int SR = THREADS / SJW;            // rows per stage chunk
    const int NTS = NT * 16 / SR;            // stage chunks per thread
    const int EPT = 1024 / THREADS;          // ul/vl elems per thread
    __shared__ __align__(16) unsigned short hls[2][NT * 16][JP];
    __shared__ float ul[1024], vl[1024];
    __shared__ float wred[NW];

    const int tid = threadIdx.x;
    const int w = tid >> 6, lane = tid & 63;
    const int n16 = lane & 15, quad = lane >> 4;
    const int hy = blockIdx.x;
    const int ibx = blockIdx.y;
    const int bz = (FS == 2) ? (blockIdx.z >> 1) : blockIdx.z;
    const int fz = (FS == 2) ? (blockIdx.z & 1) : 0;
    const int hb = hy * 8 + bz;
    const int iw0 = ibx * ITILE + w * (16 * NI);

    // raw f2L -> ul (temp) + per-wave max
    if (EPT == 4) {
        const int j4 = tid * 4;
        float4 fv = *(const float4*)(f2g + (size_t)hb * N + j4);
        fv.x *= LOG2E; fv.y *= LOG2E; fv.z *= LOG2E; fv.w *= LOG2E;
        *(float4*)&ul[j4] = fv;
        float m4 = fmaxf(fmaxf(fv.x, fv.y), fmaxf(fv.z, fv.w));
#pragma unroll
        for (int off = 32; off; off >>= 1) m4 = fmaxf(m4, __shfl_xor(m4, off));
        if (lane == 0) wred[w] = m4;
    } else {
        const int j2 = tid * 2;
        float2 fv = *(const float2*)(f2g + (size_t)hb * N + j2);
        fv.x *= LOG2E; fv.y *= LOG2E;
        *(float2*)&ul[j2] = fv;
        float m4 = fmaxf(fv.x, fv.y);
#pragma unroll
        for (int off = 32; off; off >>= 1) m4 = fmaxf(m4, __shfl_xor(m4, off));
        if (lane == 0) wred[w] = m4;
    }

    float f1L[NI];
#pragma unroll
    for (int ii = 0; ii < NI; ++ii)
        f1L[ii] = f1g[(size_t)hb * N + iw0 + ii * 16 + n16] * LOG2E;

    const unsigned short* gsrc = hT + (size_t)(hy * 128 + fz * (NT * 16)) * 8192 + bz * 1024;
    const int sf = tid / SJW, sj = (tid % SJW) * 8;

    bf16x8 stg[NTS];
#pragma unroll
    for (int s = 0; s < NTS; ++s)
        stg[s] = *(const bf16x8*)(gsrc + (size_t)(sf + SR * s) * 8192 + sj);

    __syncthreads();   // ul(raw)/wred visible
    float f2mL = wred[0];
#pragma unroll
    for (int k = 1; k < NW; ++k) f2mL = fmaxf(f2mL, wred[k]);

    // rewrite own slots: u = exp2(raw - f2mL), v = exp2(a*(raw - f2mL))
    if (EPT == 4) {
        const int j4 = tid * 4;
        float4 raw = *(const float4*)&ul[j4];
        float4 uu, vv;
        float d0 = raw.x - f2mL, d1 = raw.y - f2mL, d2 = raw.z - f2mL, d3 = raw.w - f2mL;
        uu.x = __builtin_amdgcn_exp2f(d0); vv.x = __builtin_amdgcn_exp2f(ALPHA * d0);
        uu.y = __builtin_amdgcn_exp2f(d1); vv.y = __builtin_amdgcn_exp2f(ALPHA * d1);
        uu.z = __builtin_amdgcn_exp2f(d2); vv.z = __builtin_amdgcn_exp2f(ALPHA * d2);
        uu.w = __builtin_amdgcn_exp2f(d3); vv.w = __builtin_amdgcn_exp2f(ALPHA * d3);
        *(float4*)&ul[j4] = uu;
        *(float4*)&vl[j4] = vv;
    } else {
        const int j2 = tid * 2;
        float2 raw = *(const float2*)&ul[j2];
        float d0 = raw.x - f2mL, d1 = raw.y - f2mL;
        float2 uu, vv;
        uu.x = __builtin_amdgcn_exp2f(d0); vv.x = __builtin_amdgcn_exp2f(ALPHA * d0);
        uu.y = __builtin_amdgcn_exp2f(d1); vv.y = __builtin_amdgcn_exp2f(ALPHA * d1);
        *(float2*)&ul[j2] = uu;
        *(float2*)&vl[j2] = vv;
    }

    float ri[NI];
#pragma unroll
    for (int ii = 0; ii < NI; ++ii)
        ri[ii] = __builtin_amdgcn_exp2f((ALPHA - 1.f) * (f1L[ii] + f2mL));

    f32x4 acc[NI][NT], accl[NI];
#pragma unroll
    for (int ii = 0; ii < NI; ++ii) {
        accl[ii] = (f32x4){0.f, 0.f, 0.f, 0.f};
#pragma unroll
        for (int t = 0; t < NT; ++t) acc[ii][t] = (f32x4){0.f, 0.f, 0.f, 0.f};
    }
    bf16x8 ones;
    { union { bf16x8 v; unsigned u[4]; } o;
      o.u[0] = o.u[1] = o.u[2] = o.u[3] = 0x3F803F80u; ones = o.v; }

    // stage tile 0 into buf 0
#pragma unroll
    for (int s = 0; s < NTS; ++s)
        *(bf16x8*)&hls[0][sf + SR * s][sj] = stg[s];
    __syncthreads();   // tile 0 + rewritten ul/vl visible

    for (int jt = 0; jt < N / JT; ++jt) {
        const int cur = jt & 1;
        if (jt + 1 < N / JT) {
            int j0n = (jt + 1) * JT;
#pragma unroll
            for (int s = 0; s < NTS; ++s)
                stg[s] = *(const bf16x8*)(gsrc + (size_t)(sf + SR * s) * 8192 + j0n + sj);
        }
        const int j0 = jt * JT;
#pragma unroll
        for (int kk = 0; kk < KKN; ++kk) {
            const int jb = j0 + kk * 32 + quad * 8;
            float4 u0 = *(const float4*)&ul[jb], u1 = *(const float4*)&ul[jb + 4];
            float4 v0 = *(const float4*)&vl[jb], v1 = *(const float4*)&vl[jb + 4];
            float uj[8] = {u0.x, u0.y, u0.z, u0.w, u1.x, u1.y, u1.z, u1.w};
            float vj[8] = {v0.x, v0.y, v0.z, v0.w, v1.x, v1.y, v1.z, v1.w};

            bf16x8 afr[NI];
#pragma unroll
            for (int ii = 0; ii < NI; ++ii) {
                union { bf16x8 v; unsigned u[4]; } cvt;
#pragma unroll
                for (int q = 0; q < 4; ++q) {
                    float p0 = fmaxf(uj[2 * q],     ri[ii] * vj[2 * q]);
                    float p1 = fmaxf(uj[2 * q + 1], ri[ii] * vj[2 * q + 1]);
                    cvt.u[q] = pkbf_rhu(p0, p1);
                }
                afr[ii] = cvt.v;
            }
            __builtin_amdgcn_s_setprio(1);
#pragma unroll
            for (int t = 0; t < NT; ++t) {
                bf16x8 bfr = *(const bf16x8*)&hls[cur][t * 16 + n16][kk * 32 + quad * 8];
#pragma unroll
                for (int ii = 0; ii < NI; ++ii)
                    acc[ii][t] = __builtin_amdgcn_mfma_f32_16x16x32_bf16(
                        afr[ii], bfr, acc[ii][t], 0, 0, 0);
            }
#pragma unroll
            for (int ii = 0; ii < NI; ++ii)
                accl[ii] = __builtin_amdgcn_mfma_f32_16x16x32_bf16(
                    afr[ii], ones, accl[ii], 0, 0, 0);
            __builtin_amdgcn_s_setprio(0);
        }
        if (jt + 1 < N / JT) {
#pragma unroll
            for (int s = 0; s < NTS; ++s)
                *(bf16x8*)&hls[1 - cur][sf + SR * s][sj] = stg[s];
        }
        __syncthreads();
    }

    // epilogue: C/D layout col=lane&15 (f), row=quad*4+reg (i); lsum in accl
#pragma unroll
    for (int ii = 0; ii < NI; ++ii) {
#pragma unroll
        for (int r = 0; r < 4; ++r) {
            float inv = 1.f / accl[ii][r];
            int i = iw0 + ii * 16 + quad * 4 + r;
#pragma unroll
            for (int t = 0; t < NT; ++t) {
                float tv = acc[ii][t][r] * inv;
                tv = elu1(tv);
                outb[(size_t)(bz * 1024 + i) * 1024 + hy * 128 + fz * (NT * 16) + t * 16 + n16]
                    = f2bf(tv);
            }
        }
    }
}

// ---------------------------------------------------------------------------
// MFMA attention (layer 2) — stage-once barrier-free variant (R4-proven).
// Per block: full 64f x 1024j slice resident in LDS (129 KB, pad 1032 rows
// -> ~2-way bank aliasing = free), 2 barriers total, then 16 jt iterations
// of pure p-build+MFMA with no syncs. f-split via blockIdx.z.
// grid (8=bz, 16=ibx, 2=fz), 256 threads. Output f32 with double elu.
// ---------------------------------------------------------------------------
__global__ __launch_bounds__(256) void attn5(
    const unsigned short* __restrict__ hT, const float* __restrict__ f1g,
    const float* __restrict__ f2g, float* __restrict__ outf)
{
    const int N = 1024;
    __shared__ __align__(16) unsigned short hfull[64][1032];
    __shared__ float ul[1024], vl[1024];
    __shared__ float wred[4];

    const int tid = threadIdx.x;
    const int w = tid >> 6, lane = tid & 63;
    const int n16 = lane & 15, quad = lane >> 4;
    const int bz = blockIdx.x;
    const int ibx = blockIdx.y;
    const int fz = blockIdx.z;
    const int iw0 = ibx * 64 + w * 16;

    // raw f2L -> ul (temp) + per-wave max
    const int j4 = tid * 4;
    {
        float4 fv = *(const float4*)(f2g + (size_t)bz * N + j4);
        fv.x *= LOG2E; fv.y *= LOG2E; fv.z *= LOG2E; fv.w *= LOG2E;
        *(float4*)&ul[j4] = fv;
        float m4 = fmaxf(fmaxf(fv.x, fv.y), fmaxf(fv.z, fv.w));
#pragma unroll
        for (int off = 32; off; off >>= 1) m4 = fmaxf(m4, __shfl_xor(m4, off));
        if (lane == 0) wred[w] = m4;
    }

    float f1L = f1g[(size_t)bz * N + iw0 + n16] * LOG2E;

    // stage the whole 64 x 1024 slice (once)
    const unsigned short* gsrc = hT + (size_t)(fz * 64) * 8192 + bz * 1024;
    const int sr = tid >> 3;            // 0..31
    const int sc = (tid & 7) * 8;       // 0..56
#pragma unroll
    for (int s = 0; s < 2; ++s)
#pragma unroll
        for (int c = 0; c < 16; ++c)
            *(bf16x8*)&hfull[sr + 32 * s][sc + c * 64] =
                *(const bf16x8*)(gsrc + (size_t)(sr + 32 * s) * 8192 + sc + c * 64);

    __syncthreads();   // ul(raw)/wred visible (stage writes also complete later)
    const float f2mL = fmaxf(fmaxf(wred[0], wred[1]), fmaxf(wred[2], wred[3]));

    // rewrite own slots: u = exp2(raw - f2mL), v = exp2(a*(raw - f2mL))
    {
        float4 raw = *(const float4*)&ul[j4];
        float4 uu, vv;
        float d0 = raw.x - f2mL, d1 = raw.y - f2mL, d2 = raw.z - f2mL, d3 = raw.w - f2mL;
        uu.x = __builtin_amdgcn_exp2f(d0); vv.x = __builtin_amdgcn_exp2f(ALPHA * d0);
        uu.y = __builtin_amdgcn_exp2f(d1); vv.y = __builtin_amdgcn_exp2f(ALPHA * d1);
        uu.z = __builtin_amdgcn_exp2f(d2); vv.z = __builtin_amdgcn_exp2f(ALPHA * d2);
        uu.w = __builtin_amdgcn_exp2f(d3); vv.w = __builtin_amdgcn_exp2f(ALPHA * d3);
        *(float4*)&ul[j4] = uu;
        *(float4*)&vl[j4] = vv;
    }
    const float ri = __builtin_amdgcn_exp2f((ALPHA - 1.f) * (f1L + f2mL));

    f32x4 acc[4], accl = (f32x4){0.f, 0.f, 0.f, 0.f};
#pragma unroll
    for (int t = 0; t < 4; ++t) acc[t] = (f32x4){0.f, 0.f, 0.f, 0.f};
    bf16x8 ones;
    { union { bf16x8 v; unsigned u[4]; } o;
      o.u[0] = o.u[1] = o.u[2] = o.u[3] = 0x3F803F80u; ones = o.v; }

    __syncthreads();   // rewritten ul/vl + full stage visible

    for (int jt = 0; jt < 16; ++jt) {
#pragma unroll
        for (int kk = 0; kk < 2; ++kk) {
            const int jb = jt * 64 + kk * 32 + quad * 8;
            float4 u0 = *(const float4*)&ul[jb], u1 = *(const float4*)&ul[jb + 4];
            float4 v0 = *(const float4*)&vl[jb], v1 = *(const float4*)&vl[jb + 4];
            float uj[8] = {u0.x, u0.y, u0.z, u0.w, u1.x, u1.y, u1.z, u1.w};
            float vj[8] = {v0.x, v0.y, v0.z, v0.w, v1.x, v1.y, v1.z, v1.w};

            union { bf16x8 v; unsigned u[4]; } cvt;
#pragma unroll
            for (int q = 0; q < 4; ++q) {
                float p0 = fmaxf(uj[2 * q],     ri * vj[2 * q]);
                float p1 = fmaxf(uj[2 * q + 1], ri * vj[2 * q + 1]);
                cvt.u[q] = pkbf_rhu(p0, p1);
            }
            bf16x8 afr = cvt.v;
            __builtin_amdgcn_s_setprio(1);
#pragma unroll
            for (int t = 0; t < 4; ++t) {
                bf16x8 bfr = *(const bf16x8*)&hfull[t * 16 + n16][jb];
                acc[t] = __builtin_amdgcn_mfma_f32_16x16x32_bf16(afr, bfr, acc[t], 0, 0, 0);
            }
            accl = __builtin_amdgcn_mfma_f32_16x16x32_bf16(afr, ones, accl, 0, 0, 0);
            __builtin_amdgcn_s_setprio(0);
        }
    }

    // epilogue: col=lane&15 (f), row=quad*4+reg (i); double elu; f32 out
#pragma unroll
    for (int r = 0; r < 4; ++r) {
        float inv = 1.f / accl[r];
        int i = iw0 + quad * 4 + r;
#pragma unroll
        for (int t = 0; t < 4; ++t) {
            float tv = elu1(elu1(acc[t][r] * inv));
            outf[(size_t)(bz * 1024 + i) * 128 + fz * 64 + t * 16 + n16] = tv;
        }
    }
}

// ---------------------------------------------------------------------------
// B=8, N=1024, D=256, H=8, F=128
// ---------------------------------------------------------------------------
extern "C" void kernel_launch(void* const* d_in, const int* in_sizes, int n_in,
                              void* d_out, int out_size, void* d_ws, size_t ws_size,
                              hipStream_t stream)
{
    const float* x  = (const float*)d_in[0];
    const float* Wh = (const float*)d_in[2];
    const float* ah = (const float*)d_in[3];
    const float* Wo = (const float*)d_in[4];
    const float* ao = (const float*)d_in[5];
    float* out = (float*)d_out;

    unsigned short* WhT = (unsigned short*)d_ws;       // [1024][256]
    unsigned short* WoT = WhT + 262144;                // [128][1024]
    unsigned short* h1T = WoT + 131072;                // [8][128][8192]
    unsigned short* xcb = h1T + 8388608;               // [8192][1024]
    unsigned short* h2T = xcb + 8388608;               // [128][8192]
    float* f1a  = (float*)(h2T + 1048576);             // [8][8192]
    float* f2a  = f1a + 65536;                         // [8][8192]
    float* f1b  = f2a + 65536;                         // [8192]
    float* f2b  = f1b + 8192;                          // [8192]

    // prep: both weight transposes in one launch
    cvt_w_all<<<dim3(16, 2, 9), 256, 0, stream>>>(Wh, Wo, WhT, WoT);

    // Layer 1: fused x-convert + GEMM (128x128 tile) + f1/f2 epilogue,
    // then dbuf attention (R9-best config: NI=2, NT=8, 8 waves, setprio)
    gemm_t<128, 128, 32, 64, 1, 1, 512><<<dim3(64, 8), 512, 0, stream>>>(
        x, WhT, h1T, 256, ah, f1a, f2a);
    attn4<2, 8, 512, 1><<<dim3(8, 4, 8), 512, 0, stream>>>(h1T, f1a, f2a, xcb);

    // Layer 2: GEMM with fused f1/f2 epilogue, then stage-once attention
    gemm_t<32, 128, 16, 64, 1, 0, 256><<<dim3(256, 1), 256, 0, stream>>>(
        xcb, WoT, h2T, 1024, ao, f1b, f2b);
    attn5<<<dim3(8, 16, 2), 256, 0, stream>>>(h2T, f1b, f2b, out);
}